// Round 2
// baseline (691.071 us; speedup 1.0000x reference)
//
#include <hip/hip_runtime.h>

#define LATENT 128
#define HEAD 8
#define DH 16
#define TM 32   // rows per block in GEMM

#define SCAN_BLOCK 2048    // elements scanned per block
#define SCAN_THREADS 256   // 8 elements per thread

// ---------------------------------------------------------------------------
// Kernel 1: QKV projection.  out[r][c] = sum_k emb[r][k] * W[k][c]
// ---------------------------------------------------------------------------
__global__ __launch_bounds__(256) void qkv_gemm(
    const float* __restrict__ emb,
    const float* __restrict__ Wq, const float* __restrict__ Wk, const float* __restrict__ Wv,
    float* __restrict__ Q, float* __restrict__ K, float* __restrict__ V,
    int nNodes)
{
    __shared__ float sW[LATENT * LATENT];     // 64 KB
    __shared__ float sE[TM][LATENT];          // 16 KB

    const float* W;
    float* out;
    if (blockIdx.y == 0)      { W = Wq; out = Q; }
    else if (blockIdx.y == 1) { W = Wk; out = K; }
    else                      { W = Wv; out = V; }

    const int tid  = threadIdx.x;
    const int row0 = blockIdx.x * TM;

    for (int i = tid; i < LATENT * LATENT / 4; i += 256)
        ((float4*)sW)[i] = ((const float4*)W)[i];

    for (int i = tid; i < TM * LATENT / 4; i += 256) {
        int r  = i >> 5;
        int c4 = i & 31;
        int gr = row0 + r;
        float4 v = make_float4(0.f, 0.f, 0.f, 0.f);
        if (gr < nNodes) v = ((const float4*)emb)[gr * (LATENT / 4) + c4];
        ((float4*)&sE[r][0])[c4] = v;
    }
    __syncthreads();

    const int c0 = (tid & 31) * 4;
    const int r0 = (tid >> 5) * 4;

    float acc[4][4] = {};
#pragma unroll 8
    for (int k = 0; k < LATENT; ++k) {
        float4 w4 = *(const float4*)&sW[k * LATENT + c0];
        float e0 = sE[r0 + 0][k];
        float e1 = sE[r0 + 1][k];
        float e2 = sE[r0 + 2][k];
        float e3 = sE[r0 + 3][k];
        acc[0][0] += e0 * w4.x; acc[0][1] += e0 * w4.y; acc[0][2] += e0 * w4.z; acc[0][3] += e0 * w4.w;
        acc[1][0] += e1 * w4.x; acc[1][1] += e1 * w4.y; acc[1][2] += e1 * w4.z; acc[1][3] += e1 * w4.w;
        acc[2][0] += e2 * w4.x; acc[2][1] += e2 * w4.y; acc[2][2] += e2 * w4.z; acc[2][3] += e2 * w4.w;
        acc[3][0] += e3 * w4.x; acc[3][1] += e3 * w4.y; acc[3][2] += e3 * w4.z; acc[3][3] += e3 * w4.w;
    }

#pragma unroll
    for (int r = 0; r < 4; ++r) {
        int gr = row0 + r0 + r;
        if (gr < nNodes) {
            float4 o = make_float4(acc[r][0], acc[r][1], acc[r][2], acc[r][3]);
            *(float4*)&out[gr * LATENT + c0] = o;
        }
    }
}

// ---------------------------------------------------------------------------
// CSR build: histogram -> exclusive scan (3 kernels) -> scatter
// ---------------------------------------------------------------------------
__global__ __launch_bounds__(256) void count_deg(
    const int* __restrict__ rows, int* __restrict__ deg, int nE)
{
    int e = blockIdx.x * 256 + threadIdx.x;
    if (e < nE) atomicAdd(&deg[rows[e]], 1);
}

__global__ __launch_bounds__(SCAN_THREADS) void scan_block(
    const int* __restrict__ deg, int* __restrict__ excl,
    int* __restrict__ blockSums, int n)
{
    __shared__ int sSum[SCAN_THREADS];
    int tid  = threadIdx.x;
    int base = blockIdx.x * SCAN_BLOCK + tid * 8;
    int v[8];
    int tot = 0;
#pragma unroll
    for (int i = 0; i < 8; ++i) {
        int idx = base + i;
        v[i] = (idx < n) ? deg[idx] : 0;
        tot += v[i];
    }
    sSum[tid] = tot;
    __syncthreads();
    for (int off = 1; off < SCAN_THREADS; off <<= 1) {
        int x = (tid >= off) ? sSum[tid - off] : 0;
        __syncthreads();
        sSum[tid] += x;
        __syncthreads();
    }
    int run = (tid > 0) ? sSum[tid - 1] : 0;   // exclusive prefix of this thread
#pragma unroll
    for (int i = 0; i < 8; ++i) {
        int idx = base + i;
        if (idx < n) excl[idx] = run;
        run += v[i];
    }
    if (tid == SCAN_THREADS - 1) blockSums[blockIdx.x] = sSum[SCAN_THREADS - 1];
}

__global__ void scan_top(int* __restrict__ blockSums, int nb)
{
    if (threadIdx.x == 0) {
        int run = 0;
        for (int i = 0; i < nb; ++i) {
            int x = blockSums[i];
            blockSums[i] = run;
            run += x;
        }
    }
}

__global__ __launch_bounds__(256) void scan_add(
    const int* __restrict__ excl, const int* __restrict__ blockSums,
    int* __restrict__ start, int* __restrict__ cursor, int n)
{
    int i = blockIdx.x * 256 + threadIdx.x;
    if (i < n) {
        int s = excl[i] + blockSums[i / SCAN_BLOCK];
        start[i]  = s;
        cursor[i] = s;
    }
}

__global__ __launch_bounds__(256) void scatter_edges(
    const int* __restrict__ rows, int* __restrict__ cursor,
    int* __restrict__ edgeIdx, int nE)
{
    int e = blockIdx.x * 256 + threadIdx.x;
    if (e < nE) {
        int p = atomicAdd(&cursor[rows[e]], 1);
        edgeIdx[p] = e;
    }
}

// ---------------------------------------------------------------------------
// Kernel 2: per-(edge,head) score: expAtt = exp(clip(q.k,-10,10))  (no atomics)
// ---------------------------------------------------------------------------
__global__ __launch_bounds__(256) void edge_scores(
    const float* __restrict__ Q, const float* __restrict__ K,
    const int* __restrict__ rows, const int* __restrict__ cols,
    float* __restrict__ expAtt, int nEdges)
{
    int t = blockIdx.x * 256 + threadIdx.x;
    int e = t >> 3;
    int h = t & 7;
    if (e >= nEdges) return;
    int r = rows[e];
    int c = cols[e];

    const float4* q4 = (const float4*)&Q[r * LATENT + h * DH];
    const float4* k4 = (const float4*)&K[c * LATENT + h * DH];
    float s = 0.f;
#pragma unroll
    for (int i = 0; i < 4; ++i) {
        float4 a = q4[i];
        float4 b = k4[i];
        s += a.x * b.x + a.y * b.y + a.z * b.z + a.w * b.w;
    }
    s = fminf(fmaxf(s, -10.f), 10.f);
    expAtt[e * HEAD + h] = expf(s);
}

// ---------------------------------------------------------------------------
// Kernel 3: node-centric normalize + aggregate. 128 threads per node
// (2 nodes per 256-thread block). No atomics, coalesced output stores.
// ---------------------------------------------------------------------------
__global__ __launch_bounds__(256) void node_aggregate(
    const float* __restrict__ V,
    const int* __restrict__ cols,
    const int* __restrict__ start, const int* __restrict__ deg,
    const int* __restrict__ edgeIdx,
    float* __restrict__ att,            // in: expAtt, out: normalized att
    float* __restrict__ outEmb, int nNodes)
{
    int node = blockIdx.x * 2 + (threadIdx.x >> 7);
    int d    = threadIdx.x & 127;
    if (node >= nNodes) return;
    int h   = d >> 4;
    int s   = start[node];
    int cnt = deg[node];

    float norm = 0.f;
    for (int j = 0; j < cnt; ++j) {
        int e = edgeIdx[s + j];
        norm += att[e * HEAD + h];
    }
    float rn = 1.f / (norm + 1e-8f);

    float acc = 0.f;
    for (int j = 0; j < cnt; ++j) {
        int e = edgeIdx[s + j];
        int c = cols[e];
        float a = att[e * HEAD + h] * rn;
        if ((d & 15) == 0) att[e * HEAD + h] = a;   // write normalized att once
        acc += a * V[c * LATENT + d];
    }
    outEmb[node * LATENT + d] = acc;
}

// ---------------------------------------------------------------------------
extern "C" void kernel_launch(void* const* d_in, const int* in_sizes, int n_in,
                              void* d_out, int out_size, void* d_ws, size_t ws_size,
                              hipStream_t stream)
{
    const float* emb  = (const float*)d_in[0];
    const int*   rows = (const int*)d_in[1];
    const int*   cols = (const int*)d_in[2];
    const float* Wq   = (const float*)d_in[3];
    const float* Wk   = (const float*)d_in[4];
    const float* Wv   = (const float*)d_in[5];

    const int N = in_sizes[0] / LATENT;   // 50000
    const int E = in_sizes[1];            // 800000

    float* outEmb = (float*)d_out;                         // [N,128]
    float* attOut = (float*)d_out + (size_t)N * LATENT;    // [E,8]

    float* Q = (float*)d_ws;
    float* K = Q + (size_t)N * LATENT;
    float* V = K + (size_t)N * LATENT;
    int* deg       = (int*)(V + (size_t)N * LATENT);
    int* excl      = deg + N;
    int* startArr  = excl + N;
    int* cursor    = startArr + N;
    int* blockSums = cursor + N;          // up to 64
    int* edgeIdx   = blockSums + 64;      // [E]

    hipMemsetAsync(deg, 0, (size_t)N * sizeof(int), stream);

    // 1. QKV projections
    dim3 gGemm((N + TM - 1) / TM, 3);
    qkv_gemm<<<gGemm, 256, 0, stream>>>(emb, Wq, Wk, Wv, Q, K, V, N);

    // 2. CSR build
    count_deg<<<(E + 255) / 256, 256, 0, stream>>>(rows, deg, E);
    int nb = (N + SCAN_BLOCK - 1) / SCAN_BLOCK;
    scan_block<<<nb, SCAN_THREADS, 0, stream>>>(deg, excl, blockSums, N);
    scan_top<<<1, 64, 0, stream>>>(blockSums, nb);
    scan_add<<<(N + 255) / 256, 256, 0, stream>>>(excl, blockSums, startArr, cursor, N);
    scatter_edges<<<(E + 255) / 256, 256, 0, stream>>>(rows, cursor, edgeIdx, E);

    // 3. per-edge scores
    int tScores = E * HEAD;
    edge_scores<<<(tScores + 255) / 256, 256, 0, stream>>>(Q, K, rows, cols, attOut, E);

    // 4. node-centric normalize + aggregate
    node_aggregate<<<(N + 1) / 2, 256, 0, stream>>>(V, cols, startArr, deg,
                                                    edgeIdx, attOut, outEmb, N);
}

// Round 3
// 400.796 us; speedup vs baseline: 1.7242x; 1.7242x over previous
//
#include <hip/hip_runtime.h>

#define LATENT 128
#define HEAD 8
#define DH 16
#define TM 32   // rows per block in GEMM

#define SCAN_BLOCK 2048    // elements scanned per block
#define SCAN_THREADS 256   // 8 elements per thread

// ---------------------------------------------------------------------------
// Kernel 1: QKV projection.  out[r][c] = sum_k emb[r][k] * W[k][c]
// ---------------------------------------------------------------------------
__global__ __launch_bounds__(256) void qkv_gemm(
    const float* __restrict__ emb,
    const float* __restrict__ Wq, const float* __restrict__ Wk, const float* __restrict__ Wv,
    float* __restrict__ Q, float* __restrict__ K, float* __restrict__ V,
    int nNodes)
{
    __shared__ float sW[LATENT * LATENT];     // 64 KB
    __shared__ float sE[TM][LATENT];          // 16 KB

    const float* W;
    float* out;
    if (blockIdx.y == 0)      { W = Wq; out = Q; }
    else if (blockIdx.y == 1) { W = Wk; out = K; }
    else                      { W = Wv; out = V; }

    const int tid  = threadIdx.x;
    const int row0 = blockIdx.x * TM;

    for (int i = tid; i < LATENT * LATENT / 4; i += 256)
        ((float4*)sW)[i] = ((const float4*)W)[i];

    for (int i = tid; i < TM * LATENT / 4; i += 256) {
        int r  = i >> 5;
        int c4 = i & 31;
        int gr = row0 + r;
        float4 v = make_float4(0.f, 0.f, 0.f, 0.f);
        if (gr < nNodes) v = ((const float4*)emb)[gr * (LATENT / 4) + c4];
        ((float4*)&sE[r][0])[c4] = v;
    }
    __syncthreads();

    const int c0 = (tid & 31) * 4;
    const int r0 = (tid >> 5) * 4;

    float acc[4][4] = {};
#pragma unroll 8
    for (int k = 0; k < LATENT; ++k) {
        float4 w4 = *(const float4*)&sW[k * LATENT + c0];
        float e0 = sE[r0 + 0][k];
        float e1 = sE[r0 + 1][k];
        float e2 = sE[r0 + 2][k];
        float e3 = sE[r0 + 3][k];
        acc[0][0] += e0 * w4.x; acc[0][1] += e0 * w4.y; acc[0][2] += e0 * w4.z; acc[0][3] += e0 * w4.w;
        acc[1][0] += e1 * w4.x; acc[1][1] += e1 * w4.y; acc[1][2] += e1 * w4.z; acc[1][3] += e1 * w4.w;
        acc[2][0] += e2 * w4.x; acc[2][1] += e2 * w4.y; acc[2][2] += e2 * w4.z; acc[2][3] += e2 * w4.w;
        acc[3][0] += e3 * w4.x; acc[3][1] += e3 * w4.y; acc[3][2] += e3 * w4.z; acc[3][3] += e3 * w4.w;
    }

#pragma unroll
    for (int r = 0; r < 4; ++r) {
        int gr = row0 + r0 + r;
        if (gr < nNodes) {
            float4 o = make_float4(acc[r][0], acc[r][1], acc[r][2], acc[r][3]);
            *(float4*)&out[gr * LATENT + c0] = o;
        }
    }
}

// ---------------------------------------------------------------------------
// CSR build: histogram -> exclusive scan (3 kernels) -> scatter
// ---------------------------------------------------------------------------
__global__ __launch_bounds__(256) void count_deg(
    const int* __restrict__ rows, int* __restrict__ deg, int nE)
{
    int e = blockIdx.x * 256 + threadIdx.x;
    if (e < nE) atomicAdd(&deg[rows[e]], 1);
}

__global__ __launch_bounds__(SCAN_THREADS) void scan_block(
    const int* __restrict__ deg, int* __restrict__ excl,
    int* __restrict__ blockSums, int n)
{
    __shared__ int sSum[SCAN_THREADS];
    int tid  = threadIdx.x;
    int base = blockIdx.x * SCAN_BLOCK + tid * 8;
    int v[8];
    int tot = 0;
#pragma unroll
    for (int i = 0; i < 8; ++i) {
        int idx = base + i;
        v[i] = (idx < n) ? deg[idx] : 0;
        tot += v[i];
    }
    sSum[tid] = tot;
    __syncthreads();
    for (int off = 1; off < SCAN_THREADS; off <<= 1) {
        int x = (tid >= off) ? sSum[tid - off] : 0;
        __syncthreads();
        sSum[tid] += x;
        __syncthreads();
    }
    int run = (tid > 0) ? sSum[tid - 1] : 0;
#pragma unroll
    for (int i = 0; i < 8; ++i) {
        int idx = base + i;
        if (idx < n) excl[idx] = run;
        run += v[i];
    }
    if (tid == SCAN_THREADS - 1) blockSums[blockIdx.x] = sSum[SCAN_THREADS - 1];
}

__global__ void scan_top(int* __restrict__ blockSums, int nb)
{
    if (threadIdx.x == 0) {
        int run = 0;
        for (int i = 0; i < nb; ++i) {
            int x = blockSums[i];
            blockSums[i] = run;
            run += x;
        }
    }
}

__global__ __launch_bounds__(256) void scan_add(
    const int* __restrict__ excl, const int* __restrict__ blockSums,
    int* __restrict__ start, int* __restrict__ cursor, int n)
{
    int i = blockIdx.x * 256 + threadIdx.x;
    if (i < n) {
        int s = excl[i] + blockSums[i / SCAN_BLOCK];
        start[i]  = s;
        cursor[i] = s;
    }
}

__global__ __launch_bounds__(256) void scatter_edges(
    const int* __restrict__ rows, int* __restrict__ cursor,
    int* __restrict__ edgeIdx, int nE)
{
    int e = blockIdx.x * 256 + threadIdx.x;
    if (e < nE) {
        int p = atomicAdd(&cursor[rows[e]], 1);
        edgeIdx[p] = e;
    }
}

// ---------------------------------------------------------------------------
// Kernel 2: per-(edge,head) score: expAtt = exp(clip(q.k,-10,10))
// ---------------------------------------------------------------------------
__global__ __launch_bounds__(256) void edge_scores(
    const float* __restrict__ Q, const float* __restrict__ K,
    const int* __restrict__ rows, const int* __restrict__ cols,
    float* __restrict__ expAtt, int nEdges)
{
    int t = blockIdx.x * 256 + threadIdx.x;
    int e = t >> 3;
    int h = t & 7;
    if (e >= nEdges) return;
    int r = rows[e];
    int c = cols[e];

    const float4* q4 = (const float4*)&Q[r * LATENT + h * DH];
    const float4* k4 = (const float4*)&K[c * LATENT + h * DH];
    float s = 0.f;
#pragma unroll
    for (int i = 0; i < 4; ++i) {
        float4 a = q4[i];
        float4 b = k4[i];
        s += a.x * b.x + a.y * b.y + a.z * b.z + a.w * b.w;
    }
    s = fminf(fmaxf(s, -10.f), 10.f);
    expAtt[e * HEAD + h] = expf(s);
}

// ---------------------------------------------------------------------------
// Kernel 3: node-centric fused aggregate. 32 threads per node (float4 each),
// 8 nodes per 256-thread block. SINGLE pass: acc = sum exp*V, norm = sum exp,
// then scale by rn at the end. Unroll-4 for memory-level parallelism.
// Writes rn[node,h] for the later att-normalize kernel.
// ---------------------------------------------------------------------------
__global__ __launch_bounds__(256) void node_aggregate(
    const float* __restrict__ V,
    const int* __restrict__ cols,
    const int* __restrict__ start, const int* __restrict__ deg,
    const int* __restrict__ edgeIdx,
    const float* __restrict__ expAtt,
    float* __restrict__ rnArr,          // [N,8]
    float* __restrict__ outEmb, int nNodes)
{
    int node = blockIdx.x * 8 + (threadIdx.x >> 5);
    int t    = threadIdx.x & 31;        // float4 slot: d = 4*t..4*t+3
    if (node >= nNodes) return;
    int h   = t >> 2;                   // head of this float4
    int s   = start[node];
    int cnt = deg[node];

    const float4* V4 = (const float4*)V;

    float4 acc = make_float4(0.f, 0.f, 0.f, 0.f);
    float norm = 0.f;

    int j = 0;
    for (; j + 4 <= cnt; j += 4) {
        int e0 = edgeIdx[s + j + 0];
        int e1 = edgeIdx[s + j + 1];
        int e2 = edgeIdx[s + j + 2];
        int e3 = edgeIdx[s + j + 3];
        int c0 = cols[e0], c1 = cols[e1], c2 = cols[e2], c3 = cols[e3];
        float a0 = expAtt[e0 * HEAD + h];
        float a1 = expAtt[e1 * HEAD + h];
        float a2 = expAtt[e2 * HEAD + h];
        float a3 = expAtt[e3 * HEAD + h];
        float4 v0 = V4[c0 * 32 + t];
        float4 v1 = V4[c1 * 32 + t];
        float4 v2 = V4[c2 * 32 + t];
        float4 v3 = V4[c3 * 32 + t];
        acc.x += a0 * v0.x + a1 * v1.x + a2 * v2.x + a3 * v3.x;
        acc.y += a0 * v0.y + a1 * v1.y + a2 * v2.y + a3 * v3.y;
        acc.z += a0 * v0.z + a1 * v1.z + a2 * v2.z + a3 * v3.z;
        acc.w += a0 * v0.w + a1 * v1.w + a2 * v2.w + a3 * v3.w;
        norm  += a0 + a1 + a2 + a3;
    }
    for (; j < cnt; ++j) {
        int e = edgeIdx[s + j];
        int c = cols[e];
        float a = expAtt[e * HEAD + h];
        float4 v = V4[c * 32 + t];
        acc.x += a * v.x; acc.y += a * v.y; acc.z += a * v.z; acc.w += a * v.w;
        norm  += a;
    }

    float rn = 1.f / (norm + 1e-8f);
    acc.x *= rn; acc.y *= rn; acc.z *= rn; acc.w *= rn;
    ((float4*)outEmb)[node * 32 + t] = acc;
    if ((t & 3) == 0) rnArr[node * HEAD + h] = rn;
}

// ---------------------------------------------------------------------------
// Kernel 4: normalize att in place: att[e,h] = expAtt[e,h] * rn[rows[e],h]
// ---------------------------------------------------------------------------
__global__ __launch_bounds__(256) void normalize_att(
    const int* __restrict__ rows, const float* __restrict__ rnArr,
    float* __restrict__ att, int nEdges)
{
    int tIdx = blockIdx.x * 256 + threadIdx.x;
    int e = tIdx >> 3;
    int h = tIdx & 7;
    if (e >= nEdges) return;
    int r = rows[e];
    att[e * HEAD + h] *= rnArr[r * HEAD + h];
}

// ---------------------------------------------------------------------------
extern "C" void kernel_launch(void* const* d_in, const int* in_sizes, int n_in,
                              void* d_out, int out_size, void* d_ws, size_t ws_size,
                              hipStream_t stream)
{
    const float* emb  = (const float*)d_in[0];
    const int*   rows = (const int*)d_in[1];
    const int*   cols = (const int*)d_in[2];
    const float* Wq   = (const float*)d_in[3];
    const float* Wk   = (const float*)d_in[4];
    const float* Wv   = (const float*)d_in[5];

    const int N = in_sizes[0] / LATENT;   // 50000
    const int E = in_sizes[1];            // 800000

    float* outEmb = (float*)d_out;                         // [N,128]
    float* attOut = (float*)d_out + (size_t)N * LATENT;    // [E,8]

    float* Q = (float*)d_ws;
    float* K = Q + (size_t)N * LATENT;
    float* V = K + (size_t)N * LATENT;
    float* rnArr = V + (size_t)N * LATENT;   // [N,8]
    int* deg       = (int*)(rnArr + (size_t)N * HEAD);
    int* excl      = deg + N;
    int* startArr  = excl + N;
    int* cursor    = startArr + N;
    int* blockSums = cursor + N;          // up to 64
    int* edgeIdx   = blockSums + 64;      // [E]

    hipMemsetAsync(deg, 0, (size_t)N * sizeof(int), stream);

    // 1. QKV projections
    dim3 gGemm((N + TM - 1) / TM, 3);
    qkv_gemm<<<gGemm, 256, 0, stream>>>(emb, Wq, Wk, Wv, Q, K, V, N);

    // 2. CSR build
    count_deg<<<(E + 255) / 256, 256, 0, stream>>>(rows, deg, E);
    int nb = (N + SCAN_BLOCK - 1) / SCAN_BLOCK;
    scan_block<<<nb, SCAN_THREADS, 0, stream>>>(deg, excl, blockSums, N);
    scan_top<<<1, 64, 0, stream>>>(blockSums, nb);
    scan_add<<<(N + 255) / 256, 256, 0, stream>>>(excl, blockSums, startArr, cursor, N);
    scatter_edges<<<(E + 255) / 256, 256, 0, stream>>>(rows, cursor, edgeIdx, E);

    // 3. per-edge scores (writes expAtt into att output region)
    int tScores = E * HEAD;
    edge_scores<<<(tScores + 255) / 256, 256, 0, stream>>>(Q, K, rows, cols, attOut, E);

    // 4. fused node-centric aggregate (single pass, no att writes)
    node_aggregate<<<(N + 7) / 8, 256, 0, stream>>>(V, cols, startArr, deg,
                                                    edgeIdx, attOut, rnArr,
                                                    outEmb, N);

    // 5. normalize att in place
    normalize_att<<<(tScores + 255) / 256, 256, 0, stream>>>(rows, rnArr, attOut, E);
}

// Round 6
// 288.785 us; speedup vs baseline: 2.3930x; 1.3879x over previous
//
#include <hip/hip_runtime.h>

#define LATENT 128
#define HEAD 8
#define DH 16

#define SCAN_BLOCK 2048    // elements scanned per block
#define SCAN_THREADS 256   // 8 elements per thread

typedef __attribute__((ext_vector_type(8))) short short8;
typedef __attribute__((ext_vector_type(4))) float floatx4;

__device__ inline float bf2f(unsigned short u) {
    return __uint_as_float(((unsigned int)u) << 16);
}
__device__ inline unsigned short f2bf(float f) {
    unsigned int b = __float_as_uint(f);
    b += 0x7fffu + ((b >> 16) & 1u);          // RNE
    return (unsigned short)(b >> 16);
}

// ---------------------------------------------------------------------------
// Split W into bf16 hi/lo, transposed: Wt{hi,lo}[mat][c][k] from W[mat][k][c]
// ---------------------------------------------------------------------------
__global__ __launch_bounds__(256) void convert_wt(
    const float* __restrict__ Wq, const float* __restrict__ Wk, const float* __restrict__ Wv,
    unsigned short* __restrict__ Wthi, unsigned short* __restrict__ Wtlo)
{
    int idx = blockIdx.x * 256 + threadIdx.x;
    if (idx >= 3 * LATENT * LATENT) return;
    int mat = idx >> 14;
    int r   = idx & 16383;
    int c   = r >> 7;
    int k   = r & 127;
    const float* W = (mat == 0) ? Wq : ((mat == 1) ? Wk : Wv);
    float x = W[k * LATENT + c];
    unsigned short hi = f2bf(x);
    float res = x - bf2f(hi);
    Wthi[idx] = hi;
    Wtlo[idx] = f2bf(res);
}

// ---------------------------------------------------------------------------
// Kernel 1: QKV projection via split-bf16 MFMA (fp32-accurate).
// 128x128 tile, K=128 in 4 steps of 32.  acc += Ahi*Bhi + Ahi*Blo + Alo*Bhi.
// emb is read fp32 and split to hi/lo in-register during staging.
// LDS: 4 x 32KB (Ahi, Alo, Bhi, Blo), XOR-swizzled (16B-chunk ^ (row&7)).
// Output: mat 0 (Q) -> fp32, mat 1 (K) -> bf16, mat 2 (V) -> fp32.
// ---------------------------------------------------------------------------
__global__ __launch_bounds__(256) void qkv_gemm_mfma(
    const float* __restrict__ emb,
    const unsigned short* __restrict__ Wthi, const unsigned short* __restrict__ Wtlo,
    float* __restrict__ Qf, unsigned short* __restrict__ Kb,
    float* __restrict__ Vf, int nNodes)
{
    __shared__ unsigned short sAhi[128 * 128];
    __shared__ unsigned short sAlo[128 * 128];
    __shared__ unsigned short sBhi[128 * 128];
    __shared__ unsigned short sBlo[128 * 128];   // 4 x 32 KB = 128 KB

    const int mat  = blockIdx.y;
    const int row0 = blockIdx.x * 128;
    const int tid  = threadIdx.x;
    const unsigned short* wthi = Wthi + mat * LATENT * LATENT;
    const unsigned short* wtlo = Wtlo + mat * LATENT * LATENT;

    // stage A from fp32 emb, splitting to hi/lo: 2048 16B-chunks (8 bf16 each)
#pragma unroll
    for (int it = 0; it < 8; ++it) {
        int g = it * 256 + tid;
        int r = g >> 4, c16 = g & 15;
        int gr = row0 + r;
        float x[8];
        if (gr < nNodes) {
            float4 f0 = ((const float4*)(emb + (size_t)gr * LATENT + c16 * 8))[0];
            float4 f1 = ((const float4*)(emb + (size_t)gr * LATENT + c16 * 8))[1];
            x[0] = f0.x; x[1] = f0.y; x[2] = f0.z; x[3] = f0.w;
            x[4] = f1.x; x[5] = f1.y; x[6] = f1.z; x[7] = f1.w;
        } else {
#pragma unroll
            for (int j = 0; j < 8; ++j) x[j] = 0.f;
        }
        short8 hi, lo;
#pragma unroll
        for (int j = 0; j < 8; ++j) {
            unsigned short h = f2bf(x[j]);
            hi[j] = (short)h;
            lo[j] = (short)f2bf(x[j] - bf2f(h));
        }
        int dst = r * 16 + (c16 ^ (r & 7));
        ((short8*)sAhi)[dst] = hi;
        ((short8*)sAlo)[dst] = lo;
    }
    // stage B (pre-split, pre-transposed W): 2048 16B-chunks each
#pragma unroll
    for (int it = 0; it < 8; ++it) {
        int g = it * 256 + tid;
        int r = g >> 4, c16 = g & 15;
        int dst = r * 16 + (c16 ^ (r & 7));
        ((uint4*)sBhi)[dst] = ((const uint4*)wthi)[g];
        ((uint4*)sBlo)[dst] = ((const uint4*)wtlo)[g];
    }
    __syncthreads();

    const int wid  = tid >> 6;
    const int lane = tid & 63;
    const int lrow = lane & 15;
    const int kgrp = lane >> 4;

    floatx4 acc[2][8];
#pragma unroll
    for (int rb = 0; rb < 2; ++rb)
#pragma unroll
        for (int cb = 0; cb < 8; ++cb)
            acc[rb][cb] = (floatx4){0.f, 0.f, 0.f, 0.f};

#pragma unroll
    for (int kk = 0; kk < 4; ++kk) {
        const int chunk = kk * 4 + kgrp;
        short8 ahi[2], alo[2], bhi[8], blo[8];
#pragma unroll
        for (int rb = 0; rb < 2; ++rb) {
            int rl  = wid * 32 + rb * 16 + lrow;
            int src = rl * 16 + (chunk ^ (rl & 7));
            ahi[rb] = ((const short8*)sAhi)[src];
            alo[rb] = ((const short8*)sAlo)[src];
        }
#pragma unroll
        for (int cb = 0; cb < 8; ++cb) {
            int cl  = cb * 16 + lrow;
            int src = cl * 16 + (chunk ^ (cl & 7));
            bhi[cb] = ((const short8*)sBhi)[src];
            blo[cb] = ((const short8*)sBlo)[src];
        }
#pragma unroll
        for (int rb = 0; rb < 2; ++rb)
#pragma unroll
            for (int cb = 0; cb < 8; ++cb) {
                acc[rb][cb] = __builtin_amdgcn_mfma_f32_16x16x32_bf16(
                    ahi[rb], bhi[cb], acc[rb][cb], 0, 0, 0);
                acc[rb][cb] = __builtin_amdgcn_mfma_f32_16x16x32_bf16(
                    ahi[rb], blo[cb], acc[rb][cb], 0, 0, 0);
                acc[rb][cb] = __builtin_amdgcn_mfma_f32_16x16x32_bf16(
                    alo[rb], bhi[cb], acc[rb][cb], 0, 0, 0);
            }
    }

    // C/D layout: col = lane&15, row = (lane>>4)*4 + reg   [m89-verified]
#pragma unroll
    for (int rb = 0; rb < 2; ++rb)
#pragma unroll
        for (int cb = 0; cb < 8; ++cb)
#pragma unroll
            for (int i = 0; i < 4; ++i) {
                int row = row0 + wid * 32 + rb * 16 + kgrp * 4 + i;
                int col = cb * 16 + lrow;
                if (row < nNodes) {
                    float v = acc[rb][cb][i];
                    if (mat == 0)      Qf[(size_t)row * LATENT + col] = v;
                    else if (mat == 1) Kb[(size_t)row * LATENT + col] = f2bf(v);
                    else               Vf[(size_t)row * LATENT + col] = v;
                }
            }
}

// ---------------------------------------------------------------------------
// CSR build: histogram -> exclusive scan (3 kernels) -> scatter
// ---------------------------------------------------------------------------
__global__ __launch_bounds__(256) void count_deg(
    const int* __restrict__ rows, int* __restrict__ deg, int nE)
{
    int e = blockIdx.x * 256 + threadIdx.x;
    if (e < nE) atomicAdd(&deg[rows[e]], 1);
}

__global__ __launch_bounds__(SCAN_THREADS) void scan_block(
    const int* __restrict__ deg, int* __restrict__ excl,
    int* __restrict__ blockSums, int n)
{
    __shared__ int sSum[SCAN_THREADS];
    int tid  = threadIdx.x;
    int base = blockIdx.x * SCAN_BLOCK + tid * 8;
    int v[8];
    int tot = 0;
#pragma unroll
    for (int i = 0; i < 8; ++i) {
        int idx = base + i;
        v[i] = (idx < n) ? deg[idx] : 0;
        tot += v[i];
    }
    sSum[tid] = tot;
    __syncthreads();
    for (int off = 1; off < SCAN_THREADS; off <<= 1) {
        int x = (tid >= off) ? sSum[tid - off] : 0;
        __syncthreads();
        sSum[tid] += x;
        __syncthreads();
    }
    int run = (tid > 0) ? sSum[tid - 1] : 0;
#pragma unroll
    for (int i = 0; i < 8; ++i) {
        int idx = base + i;
        if (idx < n) excl[idx] = run;
        run += v[i];
    }
    if (tid == SCAN_THREADS - 1) blockSums[blockIdx.x] = sSum[SCAN_THREADS - 1];
}

__global__ void scan_top(int* __restrict__ blockSums, int nb)
{
    if (threadIdx.x == 0) {
        int run = 0;
        for (int i = 0; i < nb; ++i) {
            int x = blockSums[i];
            blockSums[i] = run;
            run += x;
        }
    }
}

__global__ __launch_bounds__(256) void scan_add(
    const int* __restrict__ excl, const int* __restrict__ blockSums,
    int* __restrict__ start, int* __restrict__ cursor, int n)
{
    int i = blockIdx.x * 256 + threadIdx.x;
    if (i < n) {
        int s = excl[i] + blockSums[i / SCAN_BLOCK];
        start[i]  = s;
        cursor[i] = s;
    }
}

__global__ __launch_bounds__(256) void scatter_edges(
    const int* __restrict__ rows, int* __restrict__ cursor,
    int* __restrict__ edgeIdx, int nE)
{
    int e = blockIdx.x * 256 + threadIdx.x;
    if (e < nE) {
        int p = atomicAdd(&cursor[rows[e]], 1);
        edgeIdx[p] = e;
    }
}

// ---------------------------------------------------------------------------
// Kernel 2: fused node-centric scores + aggregate.
// 32 threads/node (4 lanes per head; each lane owns 4 dims), 8 nodes/block.
// Q fp32 in registers; gather K bf16 + V fp32 per edge; dot via 2x shfl_xor.
// ---------------------------------------------------------------------------
__global__ __launch_bounds__(256) void node_fused(
    const float* __restrict__ Qf, const unsigned short* __restrict__ Kb,
    const float* __restrict__ Vf,
    const int* __restrict__ cols,
    const int* __restrict__ start, const int* __restrict__ deg,
    const int* __restrict__ edgeIdx,
    float* __restrict__ attOut,         // [E,8] <- exp (pre-normalization)
    float* __restrict__ rnArr,          // [N,8]
    float* __restrict__ outEmb, int nNodes)
{
    int node = blockIdx.x * 8 + (threadIdx.x >> 5);
    int t    = threadIdx.x & 31;        // lane owns dims 4t..4t+3
    if (node >= nNodes) return;
    int h = t >> 2;

    float4 q = ((const float4*)(Qf + (size_t)node * LATENT))[t];

    int s   = start[node];
    int cnt = deg[node];

    float4 acc = make_float4(0.f, 0.f, 0.f, 0.f);
    float norm = 0.f;

#define EDGE_BODY(E_, KU_, VV_)                                                \
    {                                                                          \
        float p = q.x * bf2f(KU_.x) + q.y * bf2f(KU_.y) +                      \
                  q.z * bf2f(KU_.z) + q.w * bf2f(KU_.w);                       \
        p += __shfl_xor(p, 1);                                                 \
        p += __shfl_xor(p, 2);                                                 \
        p = fminf(fmaxf(p, -10.f), 10.f);                                      \
        float ex = expf(p);                                                    \
        if ((t & 3) == 0) attOut[(size_t)E_ * HEAD + h] = ex;                  \
        norm += ex;                                                            \
        acc.x += ex * VV_.x; acc.y += ex * VV_.y;                              \
        acc.z += ex * VV_.z; acc.w += ex * VV_.w;                              \
    }

    int j = 0;
    for (; j + 4 <= cnt; j += 4) {
        int e0 = edgeIdx[s + j + 0];
        int e1 = edgeIdx[s + j + 1];
        int e2 = edgeIdx[s + j + 2];
        int e3 = edgeIdx[s + j + 3];
        int c0 = cols[e0], c1 = cols[e1], c2 = cols[e2], c3 = cols[e3];
        ushort4 k0 = ((const ushort4*)(Kb + (size_t)c0 * LATENT))[t];
        ushort4 k1 = ((const ushort4*)(Kb + (size_t)c1 * LATENT))[t];
        ushort4 k2 = ((const ushort4*)(Kb + (size_t)c2 * LATENT))[t];
        ushort4 k3 = ((const ushort4*)(Kb + (size_t)c3 * LATENT))[t];
        float4 v0 = ((const float4*)(Vf + (size_t)c0 * LATENT))[t];
        float4 v1 = ((const float4*)(Vf + (size_t)c1 * LATENT))[t];
        float4 v2 = ((const float4*)(Vf + (size_t)c2 * LATENT))[t];
        float4 v3 = ((const float4*)(Vf + (size_t)c3 * LATENT))[t];
        EDGE_BODY(e0, k0, v0);
        EDGE_BODY(e1, k1, v1);
        EDGE_BODY(e2, k2, v2);
        EDGE_BODY(e3, k3, v3);
    }
    for (; j < cnt; ++j) {
        int e = edgeIdx[s + j];
        int c = cols[e];
        ushort4 ku = ((const ushort4*)(Kb + (size_t)c * LATENT))[t];
        float4  vu = ((const float4*)(Vf + (size_t)c * LATENT))[t];
        EDGE_BODY(e, ku, vu);
    }
#undef EDGE_BODY

    float rn = 1.f / (norm + 1e-8f);
    acc.x *= rn; acc.y *= rn; acc.z *= rn; acc.w *= rn;
    ((float4*)(outEmb + (size_t)node * LATENT))[t] = acc;
    if ((t & 3) == 0) rnArr[node * HEAD + h] = rn;
}

// ---------------------------------------------------------------------------
// Kernel 3: normalize att in place: att[e,h] = expAtt[e,h] * rn[rows[e],h]
// ---------------------------------------------------------------------------
__global__ __launch_bounds__(256) void normalize_att(
    const int* __restrict__ rows, const float* __restrict__ rnArr,
    float* __restrict__ att, int nEdges)
{
    int tIdx = blockIdx.x * 256 + threadIdx.x;
    int e = tIdx >> 3;
    int h = tIdx & 7;
    if (e >= nEdges) return;
    int r = rows[e];
    att[e * HEAD + h] *= rnArr[r * HEAD + h];
}

// ---------------------------------------------------------------------------
extern "C" void kernel_launch(void* const* d_in, const int* in_sizes, int n_in,
                              void* d_out, int out_size, void* d_ws, size_t ws_size,
                              hipStream_t stream)
{
    const float* emb  = (const float*)d_in[0];
    const int*   rows = (const int*)d_in[1];
    const int*   cols = (const int*)d_in[2];
    const float* Wq   = (const float*)d_in[3];
    const float* Wk   = (const float*)d_in[4];
    const float* Wv   = (const float*)d_in[5];

    const int N = in_sizes[0] / LATENT;   // 50000
    const int E = in_sizes[1];            // 800000

    float* outEmb = (float*)d_out;                         // [N,128]
    float* attOut = (float*)d_out + (size_t)N * LATENT;    // [E,8]

    float* Qf = (float*)d_ws;                              // [N,128] fp32
    float* Vf = Qf + (size_t)N * LATENT;                   // [N,128] fp32
    unsigned short* Kb   = (unsigned short*)(Vf + (size_t)N * LATENT); // [N,128] bf16
    unsigned short* Wthi = Kb + (size_t)N * LATENT;        // [3,128,128] bf16
    unsigned short* Wtlo = Wthi + 3 * LATENT * LATENT;
    float* rnArr = (float*)(Wtlo + 3 * LATENT * LATENT);   // [N,8]
    int* deg       = (int*)(rnArr + (size_t)N * HEAD);
    int* excl      = deg + N;
    int* startArr  = excl + N;
    int* cursor    = startArr + N;
    int* blockSums = cursor + N;          // up to 64
    int* edgeIdx   = blockSums + 64;      // [E]

    hipMemsetAsync(deg, 0, (size_t)N * sizeof(int), stream);

    // 0. split/transpose W
    convert_wt<<<(3 * LATENT * LATENT + 255) / 256, 256, 0, stream>>>(
        Wq, Wk, Wv, Wthi, Wtlo);

    // 1. QKV projections (split-bf16 MFMA, fp32-accurate)
    dim3 gGemm((N + 127) / 128, 3);
    qkv_gemm_mfma<<<gGemm, 256, 0, stream>>>(emb, Wthi, Wtlo, Qf, Kb, Vf, N);

    // 2. CSR build
    count_deg<<<(E + 255) / 256, 256, 0, stream>>>(rows, deg, E);
    int nb = (N + SCAN_BLOCK - 1) / SCAN_BLOCK;
    scan_block<<<nb, SCAN_THREADS, 0, stream>>>(deg, excl, blockSums, N);
    scan_top<<<1, 64, 0, stream>>>(blockSums, nb);
    scan_add<<<(N + 255) / 256, 256, 0, stream>>>(excl, blockSums, startArr, cursor, N);
    scatter_edges<<<(E + 255) / 256, 256, 0, stream>>>(rows, cursor, edgeIdx, E);

    // 3. fused scores + aggregate
    node_fused<<<(N + 7) / 8, 256, 0, stream>>>(Qf, Kb, Vf, cols, startArr, deg,
                                                edgeIdx, attOut, rnArr, outEmb, N);

    // 4. normalize att in place
    int tScores = E * HEAD;
    normalize_att<<<(tScores + 255) / 256, 256, 0, stream>>>(rows, rnArr, attOut, E);
}